// Round 3
// baseline (182.615 us; speedup 1.0000x reference)
//
#include <hip/hip_runtime.h>

// out[m,u] = x2[m] + w2[u] - 2 * sum_k x[m,k] * w[k,u]
// x[8*4096, 128] f32, w[128, 1024] f32, out[32768, 1024] f32
#define M_TOT 32768
#define K_DIM 128
#define U_TOT 1024

typedef short s16x8 __attribute__((ext_vector_type(8)));   // 8 bf16 as shorts
typedef float f32x4 __attribute__((ext_vector_type(4)));

// round-to-nearest-even fp32 -> bf16 (as ushort)
__device__ inline unsigned int f2bf(float f) {
    union { float f; unsigned int u; } v; v.f = f;
    unsigned int r = v.u + 0x7FFFu + ((v.u >> 16) & 1u);
    return r >> 16;
}

// One wave per row: x -> bf16 row-major + x2;  w -> w^T bf16 (u-major) + w2.
__global__ __launch_bounds__(256) void prep_kernel(
    const float* __restrict__ x, const float* __restrict__ w,
    unsigned int* __restrict__ xb, unsigned int* __restrict__ wt,
    float* __restrict__ x2, float* __restrict__ w2)
{
    const int lane = threadIdx.x & 63;
    const int gw = (blockIdx.x << 2) + (threadIdx.x >> 6);
    if (gw < M_TOT) {
        const float2 v = ((const float2*)(x + (size_t)gw * K_DIM))[lane];
        float s = v.x * v.x + v.y * v.y;
        #pragma unroll
        for (int off = 32; off; off >>= 1) s += __shfl_xor(s, off);
        xb[gw * 64 + lane] = f2bf(v.x) | (f2bf(v.y) << 16);
        if (lane == 0) x2[gw] = s;
    } else if (gw < M_TOT + U_TOT) {
        const int u = gw - M_TOT;
        const float a = w[(size_t)(2 * lane) * U_TOT + u];
        const float b = w[(size_t)(2 * lane + 1) * U_TOT + u];
        float s = a * a + b * b;
        #pragma unroll
        for (int off = 32; off; off >>= 1) s += __shfl_xor(s, off);
        wt[u * 64 + lane] = f2bf(a) | (f2bf(b) << 16);
        if (lane == 0) w2[u] = s;
    }
}

// LDS-free GEMM: 128x128 tile per block (4 waves, 2x2 of 64x64), fragments
// loaded straight from global (xb/wt are L2/L3-resident bf16), transposed
// MFMA accumulate (D[u][m]) so the epilogue stores float4 along u.
// Grid: 256 m-tiles * 8 u-tiles = 2048 blocks of 256 threads.
__global__ __launch_bounds__(256) void gemm_kernel(
    const unsigned short* __restrict__ xb, const unsigned short* __restrict__ wt,
    const float* __restrict__ x2, const float* __restrict__ w2,
    float* __restrict__ out)
{
    const int tid = threadIdx.x;
    const int wv = tid >> 6;
    const int lane = tid & 63;
    const int col = lane & 15;
    const int quad = lane >> 4;
    const int m0 = (int)(blockIdx.x >> 3) * 128;
    const int u0 = (int)(blockIdx.x & 7) * 128;
    const int wm = (wv & 1) * 64;
    const int wn = (wv >> 1) * 64;

    // Lane's base rows: A row (m) and B row (u) both indexed by col.
    const unsigned short* arow = xb + (size_t)(m0 + wm + col) * K_DIM;
    const unsigned short* brow = wt + (size_t)(u0 + wn + col) * K_DIM;

    f32x4 acc[4][4] = {};   // acc[a][b]: m-subtile a, u-subtile b

    #pragma unroll 1
    for (int kc = 0; kc < 4; ++kc) {
        const int ko = kc * 32 + quad * 8;       // 16B-aligned bf16 offset
        s16x8 af[4], bf[4];
        #pragma unroll
        for (int t = 0; t < 4; ++t) {
            af[t] = *(const s16x8*)(arow + t * 16 * K_DIM + ko);
            bf[t] = *(const s16x8*)(brow + t * 16 * K_DIM + ko);
        }
        // Swapped operands: D = W^T_frag * X_frag -> D row = u, D col = m.
        #pragma unroll
        for (int a = 0; a < 4; ++a)
            #pragma unroll
            for (int b = 0; b < 4; ++b)
                acc[a][b] = __builtin_amdgcn_mfma_f32_16x16x32_bf16(bf[b], af[a], acc[a][b], 0, 0, 0);
    }

    // D layout: matrix-row (u) = quad*4 + r, matrix-col (m) = lane&15.
    float xs[4];
    #pragma unroll
    for (int a = 0; a < 4; ++a) xs[a] = x2[m0 + wm + a * 16 + col];
    float4 ws4[4];
    #pragma unroll
    for (int b = 0; b < 4; ++b) ws4[b] = *(const float4*)&w2[u0 + wn + b * 16 + quad * 4];

    #pragma unroll
    for (int a = 0; a < 4; ++a) {
        const size_t mrow = (size_t)(m0 + wm + a * 16 + col) * U_TOT;
        #pragma unroll
        for (int b = 0; b < 4; ++b) {
            const int ub = u0 + wn + b * 16 + quad * 4;
            float4 o;
            o.x = xs[a] + ws4[b].x - 2.0f * acc[a][b][0];
            o.y = xs[a] + ws4[b].y - 2.0f * acc[a][b][1];
            o.z = xs[a] + ws4[b].z - 2.0f * acc[a][b][2];
            o.w = xs[a] + ws4[b].w - 2.0f * acc[a][b][3];
            *(float4*)&out[mrow + ub] = o;
        }
    }
}

// Fallback (workspace too small): correct fp32 path.
__global__ __launch_bounds__(256) void fallback_kernel(
    const float* __restrict__ x, const float* __restrict__ w,
    float* __restrict__ out)
{
    __shared__ float xrow[K_DIM];
    const int m = blockIdx.x;
    const int tid = threadIdx.x;
    if (tid < K_DIM) xrow[tid] = x[(size_t)m * K_DIM + tid];
    __syncthreads();
    float x2 = 0.f;
    #pragma unroll
    for (int k = 0; k < K_DIM; ++k) x2 += xrow[k] * xrow[k];
    #pragma unroll
    for (int uu = 0; uu < 4; ++uu) {
        const int u = uu * 256 + tid;
        float dot = 0.f, w2 = 0.f;
        for (int k = 0; k < K_DIM; ++k) {
            const float wv = w[(size_t)k * U_TOT + u];
            dot += xrow[k] * wv;
            w2 += wv * wv;
        }
        out[(size_t)m * U_TOT + u] = x2 + w2 - 2.0f * dot;
    }
}

extern "C" void kernel_launch(void* const* d_in, const int* in_sizes, int n_in,
                              void* d_out, int out_size, void* d_ws, size_t ws_size,
                              hipStream_t stream) {
    const float* x = (const float*)d_in[0];
    const float* w = (const float*)d_in[1];
    float* out = (float*)d_out;

    // ws layout: xb bf16[32768*128] | wt bf16[1024*128] | x2 f32[32768] | w2 f32[1024]
    const size_t need = (size_t)M_TOT * K_DIM * 2 + (size_t)U_TOT * K_DIM * 2
                      + (size_t)M_TOT * 4 + (size_t)U_TOT * 4;
    if (ws_size < need) {
        fallback_kernel<<<M_TOT, 256, 0, stream>>>(x, w, out);
        return;
    }

    unsigned short* xb = (unsigned short*)d_ws;
    unsigned short* wt = xb + (size_t)M_TOT * K_DIM;
    float* x2 = (float*)(wt + (size_t)U_TOT * K_DIM);
    float* w2 = x2 + M_TOT;

    prep_kernel<<<(M_TOT + U_TOT) / 4, 256, 0, stream>>>(x, w, (unsigned int*)xb,
                                                         (unsigned int*)wt, x2, w2);
    gemm_kernel<<<(M_TOT / 128) * (U_TOT / 128), 256, 0, stream>>>(xb, wt, x2, w2, out);
}